// Round 14
// baseline (327.245 us; speedup 1.0000x reference)
//
#include <hip/hip_runtime.h>
#include <math.h>

#define S_LEN 512
#define CH 8
#define NSEG 128
#define TBL_L0 -22.0f
#define TBL_INVH 4.0f
#define TBL_H 0.25f

__device__ __forceinline__ float fast_rcp(float x) { return __builtin_amdgcn_rcpf(x); }
__device__ __forceinline__ float fast_rsq(float x) { return __builtin_amdgcn_rsqf(x); }
__device__ __forceinline__ float exp2s(float x)    { return __builtin_amdgcn_exp2f(x); }

// quad_perm DPP add (pure VALU)
template <int CTRL>
__device__ __forceinline__ float dpp_add(float v) {
    int vi = __builtin_bit_cast(int, v);
    int t  = __builtin_amdgcn_update_dpp(vi, vi, CTRL, 0xF, 0xF, true);
    return v + __builtin_bit_cast(float, t);
}

// R13 algorithm (PWL Lambert-W table, pressure folded into startup G,
// log2-domain kappa). R14 restructure:
//  - two independent SCALAR chains per thread (points lane, lane+64) instead
//    of v2f: same issue count (pk is half-rate/component on CDNA4), but the
//    chains hide each other's rsq/table latency.
//  - x loads via wave-uniform (readfirstlane'd) base -> scalar pipe; no LDS
//    x staging at all. Finish-block x prefetched from global per chunk.
__global__ __launch_bounds__(128, 4) void prnn_kernel(
    const float* __restrict__ x,
    const float* __restrict__ W1,
    const float* __restrict__ W2,
    float* __restrict__ out)
{
    const double MUd = 3130.0 / 2.6;
    const double Cd  = 0.003407;
    const double K2d = 1.4426950408889634 / Cd;          // log2(e)/C
    const float MU      = (float)MUd;
    const float THREE_MU= (float)(3.0 * MUd);
    const float C43     = (float)(4.0 * MUd / 3.0);
    const float C23     = (float)(2.0 * MUd / 3.0);
    const float CP      = (float)(7825.0 / 3.0);
    const float Cf      = (float)Cd;
    const float R3M     = (float)(1.0 / (3.0 * MUd));
    const float AR3M    = (float)(64.8 / (3.0 * MUd));
    const float MQ      = (float)(-K2d / (3.0 * MUd));
    const float KA0     = (float)(1.4492898 + (64.8 / (3.0 * MUd)) * K2d);
    const float K2      = (float)K2d;
    const float LOG2E   = 1.4426950408889634f;
    const float LN08    = (float)(0.8 * 0.6931471805599453);

    const int tid  = threadIdx.x;
    const int lane = tid & 63;
    const int wv   = tid >> 6;
    const int bs   = __builtin_amdgcn_readfirstlane(blockIdx.x * 2 + wv);

    __shared__ float  part[2][CH][3][17];    // 3.3 KB
    __shared__ float2 wtab[NSEG];            // 1 KB

    // ---- build C*W(2^l2z) PWL table (block-shared, startup only) ----
    {
        float wn = 0.0f;
        if (tid <= NSEG) {
            const float s = TBL_L0 + (float)tid * TBL_H;
            const float z = exp2s(s);
            float w = fmaxf(LN08 * s, z * (1.0f - z));
            #pragma unroll
            for (int it = 0; it < 4; ++it) {
                const float y   = exp2s(w * LOG2E);
                const float g   = w * y;
                const float F   = g - z;
                const float Fp  = g + y;
                const float den = Fp*Fp - 0.5f*((F*y)*(2.0f + w));
                w = w - (F*Fp)*fast_rcp(den);
            }
            wn = w;
            ((float*)wtab)[tid] = wn;
        }
        __syncthreads();
        float wnext = 0.0f;
        if (tid < NSEG) wnext = ((float*)wtab)[tid + 1];
        __syncthreads();
        if (tid < NSEG) {
            const float sl = (wnext - wn) * (Cf * TBL_INVH);
            const float bi = Cf * wn - sl * (TBL_L0 + (float)tid * TBL_H);
            wtab[tid] = (float2){sl, bi};
        }
        __syncthreads();
    }

    // Per-chain weights: chain p handles material point lane + 64*p
    float D0[2][3], D1[2][3], D3[2][3], pvv[2][3], w2[2][3][3];
    #pragma unroll
    for (int p = 0; p < 2; ++p) {
        const int m = lane + 64*p;
        #pragma unroll
        for (int f = 0; f < 3; ++f) {
            const float av = W1[(m*3 + 0)*3 + f];
            const float bv = W1[(m*3 + 1)*3 + f];
            const float cv = W1[(m*3 + 2)*3 + f];
            D0[p][f]  = C43*av - C23*bv;
            D1[p][f]  = C43*bv - C23*av;
            D3[p][f]  = MU*cv;
            pvv[p][f] = CP*(av + bv);
        }
        #pragma unroll
        for (int o = 0; o < 3; ++o)
            #pragma unroll
            for (int j = 0; j < 3; ++j)
                w2[p][o][j] = W2[o*384 + m*3 + j];
    }

    // Startup G (pressure fold): G[o][f] = sum_m (w2[o][0]+w2[o][1])[m]*pv[f][m]
    float gsel0, gsel1, gsel2;
    {
        float G[3][3];
        #pragma unroll
        for (int o = 0; o < 3; ++o)
            #pragma unroll
            for (int f = 0; f < 3; ++f) {
                float g = 0.0f;
                #pragma unroll
                for (int p = 0; p < 2; ++p)
                    g += (w2[p][o][0] + w2[p][o][1]) * pvv[p][f];
                #pragma unroll
                for (int m = 1; m < 64; m <<= 1) g += __shfl_xor(g, m, 64);
                G[o][f] = g;
            }
        const int ro = lane % 3;
        gsel0 = (ro == 0) ? G[0][0] : (ro == 1) ? G[1][0] : G[2][0];
        gsel1 = (ro == 0) ? G[0][1] : (ro == 1) ? G[1][1] : G[2][1];
        gsel2 = (ro == 0) ? G[0][2] : (ro == 1) ? G[1][2] : G[2][2];
    }

    const float* xbs  = x   + (size_t)bs * (S_LEN*3);   // wave-uniform base
    float*       outb = out + (size_t)bs * (S_LEN*3);

    float sd0[2] = {0.f,0.f}, sd1[2] = {0.f,0.f}, sd3[2] = {0.f,0.f};
    float ka2[2] = {KA0, KA0};
    float xp0 = 0.f, xp1 = 0.f, xp2 = 0.f;

    const int rtt0 = (lane < 24) ? (lane / 3) : 0;

    #pragma unroll 1
    for (int tc = 0; tc < S_LEN; tc += CH) {
        // prefetch finish-block x row (3 vector loads, hidden under the body)
        const float* xrow = xbs + (tc + rtt0)*3;
        const float fx0 = xrow[0], fx1 = xrow[1], fx2 = xrow[2];

        #pragma unroll
        for (int tt = 0; tt < CH; ++tt) {
            const int t = tc + tt;
            // wave-uniform x loads (scalar pipe)
            const float x0 = xbs[t*3 + 0];
            const float x1 = xbs[t*3 + 1];
            const float x2 = xbs[t*3 + 2];
            const float dx0 = x0 - xp0, dx1 = x1 - xp1, dx2 = x2 - xp2;
            xp0 = x0; xp1 = x1; xp2 = x2;

            float cc[2][3];
            #pragma unroll
            for (int p = 0; p < 2; ++p) {
                // trial deviatoric stress: d = M*dx + sd_prev
                const float d0 = __builtin_fmaf(D0[p][0], dx0,
                                  __builtin_fmaf(D0[p][1], dx1,
                                  __builtin_fmaf(D0[p][2], dx2, sd0[p])));
                const float d1 = __builtin_fmaf(D1[p][0], dx0,
                                  __builtin_fmaf(D1[p][1], dx1,
                                  __builtin_fmaf(D1[p][2], dx2, sd1[p])));
                const float d3 = __builtin_fmaf(D3[p][0], dx0,
                                  __builtin_fmaf(D3[p][1], dx1,
                                  __builtin_fmaf(D3[p][2], dx2, sd3[p])));

                // q^2 = 3(d0^2 + d1^2 + d0 d1 + d3^2)
                const float h   = __builtin_fmaf(d0, d0,
                                   __builtin_fmaf(d1, d1,
                                   __builtin_fmaf(d0, d1, d3*d3)));
                const float dot = fmaxf(3.0f*h, 1e-24f);
                const float qi  = fast_rsq(dot);
                const float q   = dot * qi;

                // dg = max(0, u0 + C*W(2^l2z)) via PWL table
                const float u0  = __builtin_fmaf(q, R3M, -AR3M);
                const float l2z = __builtin_fmaf(q, MQ, ka2[p]);
                const float fi  = __builtin_fmaf(l2z, TBL_INVH, -TBL_L0*TBL_INVH);
                int ii = (int)fi; ii = ii < 0 ? 0 : ii;   // top clamp unneeded (l2z<=9.03)
                const float2 tb = wtab[ii];
                const float cw  = __builtin_fmaf(tb.x, l2z, tb.y);
                const float dg  = fmaxf(u0 + cw, 0.0f);

                // radial return: sd = (1 - 3mu*dg/q)*d; ka2 -= K2*dg
                const float n3q = -THREE_MU*qi;
                const float u   = __builtin_fmaf(dg, n3q, 1.0f);
                sd0[p] = u*d0; sd1[p] = u*d1; sd3[p] = u*d3;
                ka2[p] = __builtin_fmaf(dg, -K2, ka2[p]);

                // fc2 on deviatoric part
                #pragma unroll
                for (int o = 0; o < 3; ++o)
                    cc[p][o] = __builtin_fmaf(w2[p][o][0], sd0[p],
                                __builtin_fmaf(w2[p][o][1], sd1[p],
                                w2[p][o][2]*sd3[p]));
            }
            float c0 = cc[0][0] + cc[1][0];
            float c1 = cc[0][1] + cc[1][1];
            float c2 = cc[0][2] + cc[1][2];

            // 4-lane reduce via DPP quad_perm
            c0 = dpp_add<0xB1>(c0); c0 = dpp_add<0x4E>(c0);
            c1 = dpp_add<0xB1>(c1); c1 = dpp_add<0x4E>(c1);
            c2 = dpp_add<0xB1>(c2); c2 = dpp_add<0x4E>(c2);
            if ((lane & 3) == 0) {
                const int g16 = lane >> 2;
                part[wv][tt][0][g16] = c0;
                part[wv][tt][1][g16] = c1;
                part[wv][tt][2][g16] = c2;
            }
        }
        // finish (same wave, DS program order): lane r<24 -> (tt=r/3, o=r%3)
        if (lane < 24) {
            const int rtt = lane / 3;
            float s = 0.0f;
            #pragma unroll
            for (int g16 = 0; g16 < 16; ++g16) s += part[wv][rtt][lane - rtt*3][g16];
            s = __builtin_fmaf(gsel0, fx0, s);
            s = __builtin_fmaf(gsel1, fx1, s);
            s = __builtin_fmaf(gsel2, fx2, s);
            outb[tc*3 + lane] = s;
        }
    }
}

extern "C" void kernel_launch(void* const* d_in, const int* in_sizes, int n_in,
                              void* d_out, int out_size, void* d_ws, size_t ws_size,
                              hipStream_t stream) {
    const float* x  = (const float*)d_in[0];
    const float* W1 = (const float*)d_in[1];
    const float* W2 = (const float*)d_in[2];
    float* out = (float*)d_out;
    prnn_kernel<<<2048, 128, 0, stream>>>(x, W1, W2, out);
}

// Round 15
// 305.479 us; speedup vs baseline: 1.0713x; 1.0713x over previous
//
#include <hip/hip_runtime.h>
#include <math.h>

#define S_LEN 512
#define CH 16
#define NSEG 128
#define TBL_L0 -22.0f
#define TBL_INVH 4.0f
#define TBL_H 0.25f

typedef float v2f __attribute__((ext_vector_type(2)));

__device__ __forceinline__ float fast_rcp(float x) { return __builtin_amdgcn_rcpf(x); }
__device__ __forceinline__ float fast_rsq(float x) { return __builtin_amdgcn_rsqf(x); }
__device__ __forceinline__ float exp2s(float x)    { return __builtin_amdgcn_exp2f(x); }
__device__ __forceinline__ v2f rsqv(v2f a)  { return (v2f){fast_rsq(a.x), fast_rsq(a.y)}; }
__device__ __forceinline__ v2f maxv(v2f a, v2f b) { return __builtin_elementwise_max(a, b); }
__device__ __forceinline__ v2f minv(v2f a, v2f b) { return __builtin_elementwise_min(a, b); }

// quad_perm DPP add (pure VALU)
template <int CTRL>
__device__ __forceinline__ float dpp_add(float v) {
    int vi = __builtin_bit_cast(int, v);
    int t  = __builtin_amdgcn_update_dpp(vi, vi, CTRL, 0xF, 0xF, true);
    return v + __builtin_bit_cast(float, t);
}

// R13 structure (v2f point pairs, LDS-staged x, PWL Lambert-W table, G-fold,
// log2-kappa, DPP reduce, barrier-free main loop). R15 exact rewrites:
//  - table stores s(l2z) = A - 3muC*W directly -> u = min(s*qi,1),
//    tq = max(q-s,0), ka2 += MQ*tq  (radial return folded into table)
//  - sqrt(3) folded into D-maps (q^2 = h), 1/sqrt(3) into w2
//  - CH=16 (finish every 16 steps, float4 part reads)
__global__ __launch_bounds__(128, 4) void prnn_kernel(
    const float* __restrict__ x,
    const float* __restrict__ W1,
    const float* __restrict__ W2,
    float* __restrict__ out)
{
    const double MUd = 3130.0 / 2.6;
    const double Cd  = 0.003407;
    const double K2d = 1.4426950408889634 / Cd;          // log2(e)/C
    const double S3  = 1.7320508075688772;               // sqrt(3)
    const float MU_S3   = (float)(MUd * S3);
    const float C43_S3  = (float)(4.0 * MUd / 3.0 * S3);
    const float C23_S3  = (float)(2.0 * MUd / 3.0 * S3);
    const float CP      = (float)(7825.0 / 3.0);
    const float Cf      = (float)Cd;
    const float AH      = 64.8f;
    const float TMC     = (float)(3.0 * MUd * Cd);       // 3*mu*C
    const float MQ      = (float)(-K2d / (3.0 * MUd));   // -K2/(3mu)
    const float KA0     = (float)(1.4492898 + (64.8 / (3.0 * MUd)) * K2d);
    const float IS3     = (float)(1.0 / S3);
    const float LOG2E   = 1.4426950408889634f;
    const float LN08    = (float)(0.8 * 0.6931471805599453);

    const int tid  = threadIdx.x;
    const int lane = tid & 63;
    const int wv   = tid >> 6;
    const int b    = blockIdx.x * 2 + wv;

    __shared__ float2 xs01[2][S_LEN];        // 8 KB
    __shared__ float  xs2g[2][S_LEN];        // 4 KB
    __shared__ float  part[2][CH][3][17];    // 6.5 KB
    __shared__ float2 wtab[NSEG];            // 1 KB: (slope, intercept) of s(l2z)

    // ---- build s(l2z) = A - 3muC*W(2^l2z) PWL table (startup only) ----
    {
        float wn = 0.0f;
        if (tid <= NSEG) {
            const float sarg = TBL_L0 + (float)tid * TBL_H;
            const float z = exp2s(sarg);
            float w = fmaxf(LN08 * sarg, z * (1.0f - z));
            #pragma unroll
            for (int it = 0; it < 4; ++it) {
                const float y   = exp2s(w * LOG2E);
                const float g   = w * y;
                const float F   = g - z;
                const float Fp  = g + y;
                const float den = Fp*Fp - 0.5f*((F*y)*(2.0f + w));
                w = w - (F*Fp)*fast_rcp(den);
            }
            wn = w;
            ((float*)wtab)[tid] = wn;
        }
        __syncthreads();
        float wnext = 0.0f;
        if (tid < NSEG) wnext = ((float*)wtab)[tid + 1];
        __syncthreads();
        if (tid < NSEG) {
            const float sl = -TMC * (wnext - wn) * TBL_INVH;             // d s / d l2z
            const float bi = (AH - TMC * wn) - sl * (TBL_L0 + (float)tid * TBL_H);
            wtab[tid] = (float2){sl, bi};
        }
        __syncthreads();
    }

    // Fold fc1 + elasticity (scaled by sqrt3) into per-point maps
    v2f D0[3], D1[3], D3[3], pv[3];
    #pragma unroll
    for (int f = 0; f < 3; ++f) {
        const int mA = lane, mB = lane + 64;
        v2f av = (v2f){ W1[(mA*3 + 0)*3 + f], W1[(mB*3 + 0)*3 + f] };
        v2f bv = (v2f){ W1[(mA*3 + 1)*3 + f], W1[(mB*3 + 1)*3 + f] };
        v2f cv = (v2f){ W1[(mA*3 + 2)*3 + f], W1[(mB*3 + 2)*3 + f] };
        D0[f] = C43_S3*av - C23_S3*bv;
        D1[f] = C43_S3*bv - C23_S3*av;
        D3[f] = MU_S3*cv;
        pv[f] = CP*(av + bv);
    }
    v2f w2[3][3];   // scaled by 1/sqrt3 (applied to scaled sd)
    #pragma unroll
    for (int o = 0; o < 3; ++o)
        #pragma unroll
        for (int j = 0; j < 3; ++j)
            w2[o][j] = (v2f){ IS3*W2[o*384 + lane*3 + j], IS3*W2[o*384 + (lane+64)*3 + j] };

    // Startup G (pressure fold): uses UNSCALED w2 sum * pv -> scale back by S3
    float gsel0, gsel1, gsel2;
    {
        v2f w2s[3];
        #pragma unroll
        for (int o = 0; o < 3; ++o) w2s[o] = (w2[o][0] + w2[o][1]) * (float)S3;
        float G[3][3];
        #pragma unroll
        for (int o = 0; o < 3; ++o)
            #pragma unroll
            for (int f = 0; f < 3; ++f) {
                v2f gv = w2s[o] * pv[f];
                float g = gv.x + gv.y;
                #pragma unroll
                for (int m = 1; m < 64; m <<= 1) g += __shfl_xor(g, m, 64);
                G[o][f] = g;
            }
        const int ro = lane % 3;
        gsel0 = (ro == 0) ? G[0][0] : (ro == 1) ? G[1][0] : G[2][0];
        gsel1 = (ro == 0) ? G[0][1] : (ro == 1) ? G[1][1] : G[2][1];
        gsel2 = (ro == 0) ? G[0][2] : (ro == 1) ? G[1][2] : G[2][2];
    }

    // Per-wave x staging (same wave writes then reads -> DS program order)
    const float* xb = x + (size_t)b * (S_LEN*3);
    for (int i = lane; i < S_LEN; i += 64) {
        xs01[wv][i] = (float2){ xb[i*3 + 0], xb[i*3 + 1] };
        xs2g[wv][i] = xb[i*3 + 2];
    }

    v2f sd0 = (v2f){0.f,0.f}, sd1 = sd0, sd3 = sd0;
    v2f ka2 = (v2f){KA0, KA0};
    float xp0 = 0.f, xp1 = 0.f, xp2 = 0.f;
    float* outb = out + (size_t)b * (S_LEN*3);

    #pragma unroll 1
    for (int tc = 0; tc < S_LEN; tc += CH) {
        #pragma unroll
        for (int tt = 0; tt < CH; ++tt) {
            const int t = tc + tt;
            const float2 x01 = xs01[wv][t];
            const float  xv2 = xs2g[wv][t];
            const float dx0 = x01.x - xp0, dx1 = x01.y - xp1, dx2 = xv2 - xp2;
            xp0 = x01.x; xp1 = x01.y; xp2 = xv2;

            // scaled trial deviatoric stress: d = sqrt3*(M*dx) + sd_prev
            v2f d0 = D0[0]*dx0 + D0[1]*dx1 + D0[2]*dx2 + sd0;
            v2f d1 = D1[0]*dx0 + D1[1]*dx1 + D1[2]*dx2 + sd1;
            v2f d3 = D3[0]*dx0 + D3[1]*dx1 + D3[2]*dx2 + sd3;

            // q^2 = d0^2 + d1^2 + d0 d1 + d3^2  (sqrt3 already folded in)
            v2f h   = d0*d0 + d1*d1 + d0*d1 + d3*d3;
            v2f dot = maxv(h, (v2f){1e-24f,1e-24f});
            v2f qi  = rsqv(dot);
            v2f q   = dot * qi;

            // s = A - 3muC*W(2^l2z) via PWL table; u = min(s/q, 1)
            v2f l2z = q*MQ + ka2;
            const float fix = __builtin_fmaf(l2z.x, TBL_INVH, -TBL_L0*TBL_INVH);
            const float fiy = __builtin_fmaf(l2z.y, TBL_INVH, -TBL_L0*TBL_INVH);
            int ix = (int)fix; ix = ix < 0 ? 0 : ix;   // top clamp unneeded (l2z<=9.03)
            int iy = (int)fiy; iy = iy < 0 ? 0 : iy;
            const float2 tx = wtab[ix];
            const float2 ty = wtab[iy];
            v2f sv = (v2f){ __builtin_fmaf(tx.x, l2z.x, tx.y),
                            __builtin_fmaf(ty.x, l2z.y, ty.y) };
            v2f u   = minv(sv*qi, (v2f){1.0f,1.0f});
            v2f tq  = maxv(q - sv, (v2f){0.f,0.f});
            ka2 = tq*MQ + ka2;                  // ka2 -= K2*dg, dg = tq/(3mu)

            // radial return: sd = u*d (scaled basis)
            sd0 = u*d0; sd1 = u*d1; sd3 = u*d3;

            // fc2 on deviatoric part (w2 pre-scaled by 1/sqrt3)
            v2f a0 = w2[0][0]*sd0 + w2[0][1]*sd1 + w2[0][2]*sd3;
            v2f a1 = w2[1][0]*sd0 + w2[1][1]*sd1 + w2[1][2]*sd3;
            v2f a2 = w2[2][0]*sd0 + w2[2][1]*sd1 + w2[2][2]*sd3;
            float c0 = a0.x + a0.y;
            float c1 = a1.x + a1.y;
            float c2 = a2.x + a2.y;

            // 4-lane reduce via DPP quad_perm
            c0 = dpp_add<0xB1>(c0); c0 = dpp_add<0x4E>(c0);
            c1 = dpp_add<0xB1>(c1); c1 = dpp_add<0x4E>(c1);
            c2 = dpp_add<0xB1>(c2); c2 = dpp_add<0x4E>(c2);
            if ((lane & 3) == 0) {
                const int g16 = lane >> 2;
                part[wv][tt][0][g16] = c0;
                part[wv][tt][1][g16] = c1;
                part[wv][tt][2][g16] = c2;
            }
        }
        // finish (same wave, DS program order): lane r<48 -> (tt=r/3, o=r%3)
        if (lane < 48) {
            const int rtt = lane / 3, ro = lane - rtt*3;
            const float4* pp = (const float4*)&part[wv][rtt][ro][0];
            const float4 v0 = pp[0], v1 = pp[1], v2v = pp[2], v3 = pp[3];
            float s = ((v0.x + v0.y) + (v0.z + v0.w))
                    + ((v1.x + v1.y) + (v1.z + v1.w))
                    + ((v2v.x + v2v.y) + (v2v.z + v2v.w))
                    + ((v3.x + v3.y) + (v3.z + v3.w));
            const float2 xf01 = xs01[wv][tc + rtt];
            const float  xf2  = xs2g[wv][tc + rtt];
            s = __builtin_fmaf(gsel0, xf01.x, s);
            s = __builtin_fmaf(gsel1, xf01.y, s);
            s = __builtin_fmaf(gsel2, xf2,    s);
            outb[tc*3 + lane] = s;
        }
    }
}

extern "C" void kernel_launch(void* const* d_in, const int* in_sizes, int n_in,
                              void* d_out, int out_size, void* d_ws, size_t ws_size,
                              hipStream_t stream) {
    const float* x  = (const float*)d_in[0];
    const float* W1 = (const float*)d_in[1];
    const float* W2 = (const float*)d_in[2];
    float* out = (float*)d_out;
    prnn_kernel<<<2048, 128, 0, stream>>>(x, W1, W2, out);
}

// Round 16
// 289.617 us; speedup vs baseline: 1.1299x; 1.0548x over previous
//
#include <hip/hip_runtime.h>
#include <math.h>

#define S_LEN 512
#define CH 8
#define NSEG 128
#define TBL_L0 -22.0f
#define TBL_INVH 4.0f
#define TBL_H 0.25f

typedef float v2f __attribute__((ext_vector_type(2)));

__device__ __forceinline__ float fast_rcp(float x) { return __builtin_amdgcn_rcpf(x); }
__device__ __forceinline__ float fast_rsq(float x) { return __builtin_amdgcn_rsqf(x); }
__device__ __forceinline__ float exp2s(float x)    { return __builtin_amdgcn_exp2f(x); }
__device__ __forceinline__ v2f rsqv(v2f a)  { return (v2f){fast_rsq(a.x), fast_rsq(a.y)}; }
__device__ __forceinline__ v2f minv(v2f a, v2f b) { return __builtin_elementwise_min(a, b); }
__device__ __forceinline__ v2f vfma(v2f a, v2f b, v2f c) {
    return (v2f){ __builtin_fmaf(a.x, b.x, c.x), __builtin_fmaf(a.y, b.y, c.y) };
}

// quad_perm DPP add (pure VALU)
template <int CTRL>
__device__ __forceinline__ float dpp_add(float v) {
    int vi = __builtin_bit_cast(int, v);
    int t  = __builtin_amdgcn_update_dpp(vi, vi, CTRL, 0xF, 0xF, true);
    return v + __builtin_bit_cast(float, t);
}

// R15 structure (v2f point pairs, LDS-staged x, PWL s(l2z)=A-3muC*W table,
// G pressure fold, log2-kappa, DPP reduce, barrier-free main loop).
// R16: CH=8 (halve I-footprint of the unrolled body) + exact micro-trims:
//  - ka2' = l2z - u*g (g = q*MQ) replaces tq/max/fma
//  - index clamp via saturating v_cvt_u32_f32 (l2z <= 9.03 bounds the top)
//  - q^2 fma-chain seeded with eps (PSD form) instead of maxv
__global__ __launch_bounds__(128, 4) void prnn_kernel(
    const float* __restrict__ x,
    const float* __restrict__ W1,
    const float* __restrict__ W2,
    float* __restrict__ out)
{
    const double MUd = 3130.0 / 2.6;
    const double Cd  = 0.003407;
    const double K2d = 1.4426950408889634 / Cd;          // log2(e)/C
    const double S3  = 1.7320508075688772;               // sqrt(3)
    const float MU_S3   = (float)(MUd * S3);
    const float C43_S3  = (float)(4.0 * MUd / 3.0 * S3);
    const float C23_S3  = (float)(2.0 * MUd / 3.0 * S3);
    const float CP      = (float)(7825.0 / 3.0);
    const float AH      = 64.8f;
    const float TMC     = (float)(3.0 * MUd * Cd);       // 3*mu*C
    const float MQ      = (float)(-K2d / (3.0 * MUd));   // -K2/(3mu)
    const float KA0     = (float)(1.4492898 + (64.8 / (3.0 * MUd)) * K2d);
    const float IS3     = (float)(1.0 / S3);
    const float LOG2E   = 1.4426950408889634f;
    const float LN08    = (float)(0.8 * 0.6931471805599453);

    const int tid  = threadIdx.x;
    const int lane = tid & 63;
    const int wv   = tid >> 6;
    const int b    = blockIdx.x * 2 + wv;

    __shared__ float2 xs01[2][S_LEN];        // 8 KB
    __shared__ float  xs2g[2][S_LEN];        // 4 KB
    __shared__ float  part[2][CH][3][17];    // 3.3 KB
    __shared__ float2 wtab[NSEG];            // 1 KB: (slope, intercept) of s(l2z)

    // ---- build s(l2z) = A - 3muC*W(2^l2z) PWL table (startup only) ----
    {
        float wn = 0.0f;
        if (tid <= NSEG) {
            const float sarg = TBL_L0 + (float)tid * TBL_H;
            const float z = exp2s(sarg);
            float w = fmaxf(LN08 * sarg, z * (1.0f - z));
            #pragma unroll
            for (int it = 0; it < 4; ++it) {
                const float y   = exp2s(w * LOG2E);
                const float g   = w * y;
                const float F   = g - z;
                const float Fp  = g + y;
                const float den = Fp*Fp - 0.5f*((F*y)*(2.0f + w));
                w = w - (F*Fp)*fast_rcp(den);
            }
            wn = w;
            ((float*)wtab)[tid] = wn;
        }
        __syncthreads();
        float wnext = 0.0f;
        if (tid < NSEG) wnext = ((float*)wtab)[tid + 1];
        __syncthreads();
        if (tid < NSEG) {
            const float sl = -TMC * (wnext - wn) * TBL_INVH;
            const float bi = (AH - TMC * wn) - sl * (TBL_L0 + (float)tid * TBL_H);
            wtab[tid] = (float2){sl, bi};
        }
        __syncthreads();
    }

    // Fold fc1 + elasticity (scaled by sqrt3) into per-point maps
    v2f D0[3], D1[3], D3[3], pv[3];
    #pragma unroll
    for (int f = 0; f < 3; ++f) {
        const int mA = lane, mB = lane + 64;
        v2f av = (v2f){ W1[(mA*3 + 0)*3 + f], W1[(mB*3 + 0)*3 + f] };
        v2f bv = (v2f){ W1[(mA*3 + 1)*3 + f], W1[(mB*3 + 1)*3 + f] };
        v2f cv = (v2f){ W1[(mA*3 + 2)*3 + f], W1[(mB*3 + 2)*3 + f] };
        D0[f] = C43_S3*av - C23_S3*bv;
        D1[f] = C43_S3*bv - C23_S3*av;
        D3[f] = MU_S3*cv;
        pv[f] = CP*(av + bv);
    }
    v2f w2[3][3];   // scaled by 1/sqrt3 (applied to scaled sd)
    #pragma unroll
    for (int o = 0; o < 3; ++o)
        #pragma unroll
        for (int j = 0; j < 3; ++j)
            w2[o][j] = (v2f){ IS3*W2[o*384 + lane*3 + j], IS3*W2[o*384 + (lane+64)*3 + j] };

    // Startup G (pressure fold)
    float gsel0, gsel1, gsel2;
    {
        v2f w2s[3];
        #pragma unroll
        for (int o = 0; o < 3; ++o) w2s[o] = (w2[o][0] + w2[o][1]) * (float)S3;
        float G[3][3];
        #pragma unroll
        for (int o = 0; o < 3; ++o)
            #pragma unroll
            for (int f = 0; f < 3; ++f) {
                v2f gv = w2s[o] * pv[f];
                float g = gv.x + gv.y;
                #pragma unroll
                for (int m = 1; m < 64; m <<= 1) g += __shfl_xor(g, m, 64);
                G[o][f] = g;
            }
        const int ro = lane % 3;
        gsel0 = (ro == 0) ? G[0][0] : (ro == 1) ? G[1][0] : G[2][0];
        gsel1 = (ro == 0) ? G[0][1] : (ro == 1) ? G[1][1] : G[2][1];
        gsel2 = (ro == 0) ? G[0][2] : (ro == 1) ? G[1][2] : G[2][2];
    }

    // Per-wave x staging (same wave writes then reads -> DS program order)
    const float* xb = x + (size_t)b * (S_LEN*3);
    for (int i = lane; i < S_LEN; i += 64) {
        xs01[wv][i] = (float2){ xb[i*3 + 0], xb[i*3 + 1] };
        xs2g[wv][i] = xb[i*3 + 2];
    }

    v2f sd0 = (v2f){0.f,0.f}, sd1 = sd0, sd3 = sd0;
    v2f ka2 = (v2f){KA0, KA0};
    float xp0 = 0.f, xp1 = 0.f, xp2 = 0.f;
    float* outb = out + (size_t)b * (S_LEN*3);

    #pragma unroll 1
    for (int tc = 0; tc < S_LEN; tc += CH) {
        #pragma unroll
        for (int tt = 0; tt < CH; ++tt) {
            const int t = tc + tt;
            const float2 x01 = xs01[wv][t];
            const float  xv2 = xs2g[wv][t];
            const float dx0 = x01.x - xp0, dx1 = x01.y - xp1, dx2 = xv2 - xp2;
            xp0 = x01.x; xp1 = x01.y; xp2 = xv2;

            // scaled trial deviatoric stress: d = sqrt3*(M*dx) + sd_prev
            v2f d0 = D0[0]*dx0 + D0[1]*dx1 + D0[2]*dx2 + sd0;
            v2f d1 = D1[0]*dx0 + D1[1]*dx1 + D1[2]*dx2 + sd1;
            v2f d3 = D3[0]*dx0 + D3[1]*dx1 + D3[2]*dx2 + sd3;

            // q^2 = d0^2 + d1^2 + d0 d1 + d3^2 + eps  (PSD, eps-seeded)
            v2f h = vfma(d0, d0, vfma(d1, d1, vfma(d0, d1,
                      vfma(d3, d3, (v2f){1e-24f, 1e-24f}))));
            v2f qi  = rsqv(h);
            v2f q   = h * qi;

            // s = A - 3muC*W(2^l2z) via PWL table; g = q*MQ; l2z = g + ka2
            v2f g   = q * MQ;
            v2f l2z = g + ka2;
            const float fix = __builtin_fmaf(l2z.x, TBL_INVH, -TBL_L0*TBL_INVH);
            const float fiy = __builtin_fmaf(l2z.y, TBL_INVH, -TBL_L0*TBL_INVH);
            const unsigned ix = (unsigned)fix;   // saturating cvt: <0 and NaN -> 0
            const unsigned iy = (unsigned)fiy;   // top bounded: l2z<=9.03 -> ii<=124
            const float2 tx = wtab[ix];
            const float2 ty = wtab[iy];
            v2f sv = (v2f){ __builtin_fmaf(tx.x, l2z.x, tx.y),
                            __builtin_fmaf(ty.x, l2z.y, ty.y) };
            v2f u   = minv(sv*qi, (v2f){1.0f,1.0f});
            ka2 = vfma(-u, g, l2z);              // == ka2 + MQ*max(q-s,0), exact

            // radial return: sd = u*d (scaled basis)
            sd0 = u*d0; sd1 = u*d1; sd3 = u*d3;

            // fc2 on deviatoric part (w2 pre-scaled by 1/sqrt3)
            v2f a0 = w2[0][0]*sd0 + w2[0][1]*sd1 + w2[0][2]*sd3;
            v2f a1 = w2[1][0]*sd0 + w2[1][1]*sd1 + w2[1][2]*sd3;
            v2f a2 = w2[2][0]*sd0 + w2[2][1]*sd1 + w2[2][2]*sd3;
            float c0 = a0.x + a0.y;
            float c1 = a1.x + a1.y;
            float c2 = a2.x + a2.y;

            // 4-lane reduce via DPP quad_perm
            c0 = dpp_add<0xB1>(c0); c0 = dpp_add<0x4E>(c0);
            c1 = dpp_add<0xB1>(c1); c1 = dpp_add<0x4E>(c1);
            c2 = dpp_add<0xB1>(c2); c2 = dpp_add<0x4E>(c2);
            if ((lane & 3) == 0) {
                const int g16 = lane >> 2;
                part[wv][tt][0][g16] = c0;
                part[wv][tt][1][g16] = c1;
                part[wv][tt][2][g16] = c2;
            }
        }
        // finish (same wave, DS program order): lane r<24 -> (tt=r/3, o=r%3)
        if (lane < 24) {
            const int rtt = lane / 3, ro = lane - rtt*3;
            const float4* pp = (const float4*)&part[wv][rtt][ro][0];
            const float4 v0 = pp[0], v1 = pp[1], v2v = pp[2], v3 = pp[3];
            float s = ((v0.x + v0.y) + (v0.z + v0.w))
                    + ((v1.x + v1.y) + (v1.z + v1.w))
                    + ((v2v.x + v2v.y) + (v2v.z + v2v.w))
                    + ((v3.x + v3.y) + (v3.z + v3.w));
            const float2 xf01 = xs01[wv][tc + rtt];
            const float  xf2  = xs2g[wv][tc + rtt];
            s = __builtin_fmaf(gsel0, xf01.x, s);
            s = __builtin_fmaf(gsel1, xf01.y, s);
            s = __builtin_fmaf(gsel2, xf2,    s);
            outb[tc*3 + lane] = s;
        }
    }
}

extern "C" void kernel_launch(void* const* d_in, const int* in_sizes, int n_in,
                              void* d_out, int out_size, void* d_ws, size_t ws_size,
                              hipStream_t stream) {
    const float* x  = (const float*)d_in[0];
    const float* W1 = (const float*)d_in[1];
    const float* W2 = (const float*)d_in[2];
    float* out = (float*)d_out;
    prnn_kernel<<<2048, 128, 0, stream>>>(x, W1, W2, out);
}

// Round 17
// 275.456 us; speedup vs baseline: 1.1880x; 1.0514x over previous
//
#include <hip/hip_runtime.h>
#include <math.h>

#define S_LEN 512
#define CH 8
#define NSEG 128
#define TBL_L0 -22.0f
#define TBL_INVH 4.0f
#define TBL_H 0.25f

typedef float v2f __attribute__((ext_vector_type(2)));

__device__ __forceinline__ float fast_rcp(float x) { return __builtin_amdgcn_rcpf(x); }
__device__ __forceinline__ float fast_rsq(float x) { return __builtin_amdgcn_rsqf(x); }
__device__ __forceinline__ float exp2s(float x)    { return __builtin_amdgcn_exp2f(x); }
__device__ __forceinline__ v2f rsqv(v2f a)  { return (v2f){fast_rsq(a.x), fast_rsq(a.y)}; }
__device__ __forceinline__ v2f minv(v2f a, v2f b) { return __builtin_elementwise_min(a, b); }
__device__ __forceinline__ v2f vfma(v2f a, v2f b, v2f c) {
    return (v2f){ __builtin_fmaf(a.x, b.x, c.x), __builtin_fmaf(a.y, b.y, c.y) };
}

// quad_perm DPP add (pure VALU)
template <int CTRL>
__device__ __forceinline__ float dpp_add(float v) {
    int vi = __builtin_bit_cast(int, v);
    int t  = __builtin_amdgcn_update_dpp(vi, vi, CTRL, 0xF, 0xF, true);
    return v + __builtin_bit_cast(float, t);
}

// R16 structure. R17 exact rewrites:
//  - 45-deg rotation in (d0,d1): q^2 = p^2 + m^2 + d3^2 (h-chain 4->3);
//    fc2 rows become wp=(w0+w1)/3, wm=(w0-w1)/sqrt3, w3=w2/sqrt3.
//  - dx staged in LDS (per-step x-subtract and xp state eliminated);
//    finish-block absolute x prefetched from global per chunk.
__global__ __launch_bounds__(128, 4) void prnn_kernel(
    const float* __restrict__ x,
    const float* __restrict__ W1,
    const float* __restrict__ W2,
    float* __restrict__ out)
{
    const double MUd = 3130.0 / 2.6;
    const double Cd  = 0.003407;
    const double K2d = 1.4426950408889634 / Cd;          // log2(e)/C
    const double S3  = 1.7320508075688772;
    const float MU      = (float)MUd;
    const float MUS3    = (float)(MUd * S3);
    const float CP      = (float)(7825.0 / 3.0);
    const float AH      = 64.8f;
    const float TMC     = (float)(3.0 * MUd * Cd);       // 3*mu*C
    const float MQ      = (float)(-K2d / (3.0 * MUd));   // -K2/(3mu)
    const float KA0     = (float)(1.4492898 + (64.8 / (3.0 * MUd)) * K2d);
    const float I3      = (float)(1.0 / 3.0);
    const float IS3     = (float)(1.0 / S3);
    const float LOG2E   = 1.4426950408889634f;
    const float LN08    = (float)(0.8 * 0.6931471805599453);

    const int tid  = threadIdx.x;
    const int lane = tid & 63;
    const int wv   = tid >> 6;
    const int b    = blockIdx.x * 2 + wv;

    __shared__ float2 xs01[2][S_LEN];        // dx0,dx1 (8 KB)
    __shared__ float  xs2g[2][S_LEN];        // dx2 (4 KB)
    __shared__ float  part[2][CH][3][17];    // 3.3 KB
    __shared__ float2 wtab[NSEG];            // 1 KB

    // ---- build s(l2z) = A - 3muC*W(2^l2z) PWL table (startup only) ----
    {
        float wn = 0.0f;
        if (tid <= NSEG) {
            const float sarg = TBL_L0 + (float)tid * TBL_H;
            const float z = exp2s(sarg);
            float w = fmaxf(LN08 * sarg, z * (1.0f - z));
            #pragma unroll
            for (int it = 0; it < 4; ++it) {
                const float y   = exp2s(w * LOG2E);
                const float g   = w * y;
                const float F   = g - z;
                const float Fp  = g + y;
                const float den = Fp*Fp - 0.5f*((F*y)*(2.0f + w));
                w = w - (F*Fp)*fast_rcp(den);
            }
            wn = w;
            ((float*)wtab)[tid] = wn;
        }
        __syncthreads();
        float wnext = 0.0f;
        if (tid < NSEG) wnext = ((float*)wtab)[tid + 1];
        __syncthreads();
        if (tid < NSEG) {
            const float sl = -TMC * (wnext - wn) * TBL_INVH;
            const float bi = (AH - TMC * wn) - sl * (TBL_L0 + (float)tid * TBL_H);
            wtab[tid] = (float2){sl, bi};
        }
        __syncthreads();
    }

    // Rotated per-point maps: p-row = mu*(a+b), m-row = sqrt3*mu*(a-b), d3-row = sqrt3*mu*c
    v2f P[3], Mr[3], T3[3], pv[3];
    #pragma unroll
    for (int f = 0; f < 3; ++f) {
        const int mA = lane, mB = lane + 64;
        v2f av = (v2f){ W1[(mA*3 + 0)*3 + f], W1[(mB*3 + 0)*3 + f] };
        v2f bv = (v2f){ W1[(mA*3 + 1)*3 + f], W1[(mB*3 + 1)*3 + f] };
        v2f cv = (v2f){ W1[(mA*3 + 2)*3 + f], W1[(mB*3 + 2)*3 + f] };
        P[f]  = MU*(av + bv);
        Mr[f] = MUS3*(av - bv);
        T3[f] = MUS3*cv;
        pv[f] = CP*(av + bv);
    }
    // fc2 rows in rotated basis; raw w2 kept for the G-fold below
    v2f wp[3], wm[3], w3[3];
    float w2raw[2][3][2];   // [p][o][j=0,1 sum/needed] — just compute G inline
    float gsel0, gsel1, gsel2;
    {
        float G[3][3];
        #pragma unroll
        for (int o = 0; o < 3; ++o) {
            v2f w0 = (v2f){ W2[o*384 + lane*3 + 0], W2[o*384 + (lane+64)*3 + 0] };
            v2f w1 = (v2f){ W2[o*384 + lane*3 + 1], W2[o*384 + (lane+64)*3 + 1] };
            v2f wsh= (v2f){ W2[o*384 + lane*3 + 2], W2[o*384 + (lane+64)*3 + 2] };
            wp[o] = I3 *(w0 + w1);
            wm[o] = IS3*(w0 - w1);
            w3[o] = IS3*wsh;
            v2f ws = w0 + w1;
            #pragma unroll
            for (int f = 0; f < 3; ++f) {
                v2f gv = ws * pv[f];
                float g = gv.x + gv.y;
                #pragma unroll
                for (int mm = 1; mm < 64; mm <<= 1) g += __shfl_xor(g, mm, 64);
                G[o][f] = g;
            }
        }
        const int ro = lane % 3;
        gsel0 = (ro == 0) ? G[0][0] : (ro == 1) ? G[1][0] : G[2][0];
        gsel1 = (ro == 0) ? G[0][1] : (ro == 1) ? G[1][1] : G[2][1];
        gsel2 = (ro == 0) ? G[0][2] : (ro == 1) ? G[1][2] : G[2][2];
    }

    // Per-wave dx staging (same wave writes then reads -> DS program order)
    const float* xb = x + (size_t)b * (S_LEN*3);
    for (int i = lane; i < S_LEN; i += 64) {
        const float c0 = xb[i*3 + 0], c1 = xb[i*3 + 1], c2 = xb[i*3 + 2];
        float p0 = 0.f, p1 = 0.f, p2 = 0.f;
        if (i > 0) { p0 = xb[i*3 - 3]; p1 = xb[i*3 - 2]; p2 = xb[i*3 - 1]; }
        xs01[wv][i] = (float2){ c0 - p0, c1 - p1 };
        xs2g[wv][i] = c2 - p2;
    }

    v2f sp = (v2f){0.f,0.f}, sm = sp, s3 = sp;
    v2f ka2 = (v2f){KA0, KA0};
    float* outb = out + (size_t)b * (S_LEN*3);
    const int rtt0 = (lane < 24) ? (lane / 3) : 0;

    #pragma unroll 1
    for (int tc = 0; tc < S_LEN; tc += CH) {
        // prefetch finish-block absolute x (3 scalars, hidden under the body)
        const float* xrow = xb + (size_t)(tc + rtt0)*3;
        const float fx0 = xrow[0], fx1 = xrow[1], fx2 = xrow[2];

        #pragma unroll
        for (int tt = 0; tt < CH; ++tt) {
            const int t = tc + tt;
            const float2 dx01 = xs01[wv][t];
            const float  dx2  = xs2g[wv][t];
            const float dx0 = dx01.x, dx1 = dx01.y;

            // rotated trial: (p, m, d3) = R*dx + state
            v2f p  = P[0]*dx0 + P[1]*dx1 + P[2]*dx2 + sp;
            v2f m  = Mr[0]*dx0 + Mr[1]*dx1 + Mr[2]*dx2 + sm;
            v2f d3 = T3[0]*dx0 + T3[1]*dx1 + T3[2]*dx2 + s3;

            // q^2 = p^2 + m^2 + d3^2 + eps
            v2f h = vfma(p, p, vfma(m, m, vfma(d3, d3, (v2f){1e-24f,1e-24f})));
            v2f qi = rsqv(h);
            v2f q  = h * qi;

            // s = A - 3muC*W(2^l2z); l2z = q*MQ + ka2
            v2f g   = q * MQ;
            v2f l2z = g + ka2;
            const float fix = __builtin_fmaf(l2z.x, TBL_INVH, -TBL_L0*TBL_INVH);
            const float fiy = __builtin_fmaf(l2z.y, TBL_INVH, -TBL_L0*TBL_INVH);
            const unsigned ix = (unsigned)fix;   // saturating cvt (<0, NaN -> 0)
            const unsigned iy = (unsigned)fiy;   // top bounded by l2z <= 9.03
            const float2 tx = wtab[ix];
            const float2 ty = wtab[iy];
            v2f sv = (v2f){ __builtin_fmaf(tx.x, l2z.x, tx.y),
                            __builtin_fmaf(ty.x, l2z.y, ty.y) };
            v2f u   = minv(sv*qi, (v2f){1.0f,1.0f});
            ka2 = vfma(-u, g, l2z);              // exact: ka2 + MQ*max(q-s,0)

            // radial return in rotated basis
            sp = u*p; sm = u*m; s3 = u*d3;

            // fc2 (rotated rows)
            v2f a0 = wp[0]*sp + wm[0]*sm + w3[0]*s3;
            v2f a1 = wp[1]*sp + wm[1]*sm + w3[1]*s3;
            v2f a2 = wp[2]*sp + wm[2]*sm + w3[2]*s3;
            float c0 = a0.x + a0.y;
            float c1 = a1.x + a1.y;
            float c2 = a2.x + a2.y;

            // 4-lane reduce via DPP quad_perm
            c0 = dpp_add<0xB1>(c0); c0 = dpp_add<0x4E>(c0);
            c1 = dpp_add<0xB1>(c1); c1 = dpp_add<0x4E>(c1);
            c2 = dpp_add<0xB1>(c2); c2 = dpp_add<0x4E>(c2);
            if ((lane & 3) == 0) {
                const int g16 = lane >> 2;
                part[wv][tt][0][g16] = c0;
                part[wv][tt][1][g16] = c1;
                part[wv][tt][2][g16] = c2;
            }
        }
        // finish (same wave, DS program order): lane r<24 -> (tt=r/3, o=r%3)
        if (lane < 24) {
            const int rtt = lane / 3, ro = lane - rtt*3;
            const float4* pp = (const float4*)&part[wv][rtt][ro][0];
            const float4 v0 = pp[0], v1 = pp[1], v2v = pp[2], v3 = pp[3];
            float s = ((v0.x + v0.y) + (v0.z + v0.w))
                    + ((v1.x + v1.y) + (v1.z + v1.w))
                    + ((v2v.x + v2v.y) + (v2v.z + v2v.w))
                    + ((v3.x + v3.y) + (v3.z + v3.w));
            s = __builtin_fmaf(gsel0, fx0, s);
            s = __builtin_fmaf(gsel1, fx1, s);
            s = __builtin_fmaf(gsel2, fx2, s);
            outb[tc*3 + lane] = s;
        }
    }
}

extern "C" void kernel_launch(void* const* d_in, const int* in_sizes, int n_in,
                              void* d_out, int out_size, void* d_ws, size_t ws_size,
                              hipStream_t stream) {
    const float* x  = (const float*)d_in[0];
    const float* W1 = (const float*)d_in[1];
    const float* W2 = (const float*)d_in[2];
    float* out = (float*)d_out;
    prnn_kernel<<<2048, 128, 0, stream>>>(x, W1, W2, out);
}